// Round 9
// baseline (195.886 us; speedup 1.0000x reference)
//
#include <hip/hip_runtime.h>
#include <hip/hip_cooperative_groups.h>
#include <math.h>

// Problem constants (fixed by setup_inputs)
constexpr int BB = 512;    // batch (GEMM M)
constexpr int DD = 512;    // features (GEMM K)
constexpr int CC = 1000;   // classes
constexpr int CP = 1024;   // padded classes (GEMM N)
constexpr int RP = 528;    // padded row length (shorts): 1056 B, 16B-aligned,
                           // breaks 256B/1KB channel periodicity
constexpr float EPSF = 0.3f;

// ONE cooperative kernel (512 blocks x 256 thr, 2 blocks/CU co-resident).
// K[b,c]^2 = nj[b] + nc[c] - 2*dot(col_jb, col_c); dot via bf16 MFMA.
// Phase 1: blocks 0-127 argmax/ymax per row + fused y->out copy;
//          blocks 128-191 kW -> Wt (bf16 transpose via LDS, zero-padded,
//          coalesced 16B writes) + fp32 column-norm partials (4 d-chunks).
// grid.sync()  (harness supports hipLaunchCooperativeKernel)
// Phase 2: all blocks: 4 wave-tiles of 16x16 (batch x class) each; A-side
//          indexes Wt rows through wj[] (Q[b,:] == row j_b of Wt; nj == nc[j]);
//          32 fragments register-prefetched, 16 MFMAs back-to-back; epilogue
//          computes candidates in-register, butterfly row-max, atomicMax
//          (float-as-int; all candidates positive — validated R5-R8).
//
// ws layout (16B-aligned):
//   Wt    [1024*528] ushort @ 0        (1081 KB)
//   normp [4*1024]   float  @ 1088 KB  (16 KB)
//   wj    [512]      int    @ +16 KB
//   wymax [512]      float  @ +2 KB

using short8 = __attribute__((ext_vector_type(8))) short;
using us8    = __attribute__((ext_vector_type(8))) unsigned short;
using f32x4  = __attribute__((ext_vector_type(4))) float;

__device__ inline unsigned short f2bf(float f) {   // RNE float->bf16
  unsigned u = __float_as_uint(f);
  return (unsigned short)((u + 0x7FFFu + ((u >> 16) & 1u)) >> 16);
}

__global__ __launch_bounds__(256, 2)
void lm_coop(const float* __restrict__ y, const float* __restrict__ kW,
             unsigned short* __restrict__ Wt, float* __restrict__ normp,
             int* __restrict__ wj, float* __restrict__ wymax,
             float* __restrict__ out) {
  __shared__ float nsum[4][64];
  __shared__ __align__(16) unsigned short tile[64][136];  // 17.4 KB staging

  const int t = threadIdx.x;
  const int w = t >> 6, lane = t & 63;
  const int blk = blockIdx.x;

  // ================= phase 1 =================
  if (blk < 128) {
    // ---- argmax/ymax, one wave per row, + fused y->out copy ----
    const int b = blk * 4 + w;
    const float* yr = y + (size_t)b * CC;
    float bv = -INFINITY; int bi = 0;
    #pragma unroll
    for (int k = 0; k < 4; ++k) {
      const int c4 = (lane + k * 64) * 4;   // ascending per lane -> '>' keeps lowest
      if (c4 < CC) {
        const float4 v = *(const float4*)(yr + c4);
        if (v.x > bv) { bv = v.x; bi = c4; }
        if (v.y > bv) { bv = v.y; bi = c4 + 1; }
        if (v.z > bv) { bv = v.z; bi = c4 + 2; }
        if (v.w > bv) { bv = v.w; bi = c4 + 3; }
        float* orow = out + (size_t)b * (CC + 1) + c4;  // scalar stores (row stride 1001)
        orow[0] = v.x; orow[1] = v.y; orow[2] = v.z; orow[3] = v.w;
      }
    }
    #pragma unroll
    for (int off = 32; off > 0; off >>= 1) {
      const float ov = __shfl_down(bv, off);
      const int   oi = __shfl_down(bi, off);
      if (ov > bv || (ov == bv && oi < bi)) { bv = ov; bi = oi; }
    }
    if (lane == 0) { wj[b] = bi; wymax[b] = bv; }
  } else if (blk < 192) {
    // ---- transpose kW -> Wt (LDS-staged) + fp32 norm partials ----
    const int tb = blk - 128;            // 0..63
    const int cs = tb & 15, dc = tb >> 4;
    const int c0 = cs * 64, d0 = dc * 128;
    const int c = c0 + lane;
    const bool cok = (c < CC);
    float s = 0.f;
    #pragma unroll 8
    for (int it = 0; it < 32; ++it) {
      const int dd = w + it * 4;                    // 0..127
      const float v = cok ? kW[(size_t)(d0 + dd) * CC + c] : 0.f;
      s += v * v;
      tile[lane][dd] = f2bf(v);
    }
    nsum[w][lane] = s;
    __syncthreads();
    if (w == 0)
      normp[(size_t)dc * CP + c] = nsum[0][lane] + nsum[1][lane] + nsum[2][lane] + nsum[3][lane];
    // coalesced 16B writes of the transposed tile
    #pragma unroll
    for (int k = 0; k < 4; ++k) {
      const int lin = t * 4 + k;                    // 0..1023
      const int cc = lin >> 4, ch = lin & 15;
      *(us8*)(Wt + (size_t)(c0 + cc) * RP + d0 + ch * 8) =
          *(const us8*)(&tile[cc][ch * 8]);
    }
  }

  __threadfence();                       // device-scope: Wt/normp/wj visible across XCDs
  cooperative_groups::this_grid().sync();

  // ================= phase 2: GEMM + fused epilogue =================
  const int tile_id = blk * 4 + w;              // 0..2047
  const int m0 = (tile_id >> 6) * 16;           // 32 m-tiles (batch)
  const int n0 = (tile_id & 63) * 16;           // 64 n-tiles (classes)

  const int fr = lane & 15;            // A: m-row / B: n-row / C: col
  const int quad = lane >> 4;          // A/B: k-offset quad*8; C: row quad*4+reg

  const int ja = wj[m0 + fr];          // A-side: row j of Wt IS column j of kW
  const unsigned short* ap = Wt + (size_t)ja * RP + quad * 8;
  const unsigned short* bp = Wt + (size_t)(n0 + fr) * RP + quad * 8;

  // register-prefetch the whole K-slab (32 independent 16B loads), then MFMA
  short8 af[16], bf[16];
  #pragma unroll
  for (int k = 0; k < 16; ++k) {
    af[k] = *(const short8*)(ap + k * 32);
    bf[k] = *(const short8*)(bp + k * 32);
  }
  f32x4 acc = {0.f, 0.f, 0.f, 0.f};
  #pragma unroll
  for (int k = 0; k < 16; ++k)
    acc = __builtin_amdgcn_mfma_f32_16x16x32_bf16(af[k], bf[k], acc, 0, 0, 0);

  // ---- fused epilogue: candidates + butterfly row-max + atomicMax ----
  const int col = n0 + fr;             // class
  const bool cok = (col < CC);
  float nc = 0.f;
  if (cok) {
    #pragma unroll
    for (int dc = 0; dc < 4; ++dc) nc += normp[(size_t)dc * CP + col];
  }

  #pragma unroll
  for (int r = 0; r < 4; ++r) {
    const int row = m0 + quad * 4 + r; // batch
    float cd = -INFINITY;
    if (cok) {
      const int jr = wj[row];
      const float nj = normp[jr] + normp[CP + jr] + normp[2 * CP + jr] + normp[3 * CP + jr];
      const float yv = y[(size_t)row * CC + col];
      const float ym = wymax[row];
      const float k2 = nj + nc - 2.f * acc[r];
      cd = (yv == ym) ? -INFINITY : yv + EPSF * sqrtf(fmaxf(k2, 0.f) + 1e-10f);
    }
    #pragma unroll
    for (int m = 1; m < 16; m <<= 1)   // reduce over the 16 cols (same quad group)
      cd = fmaxf(cd, __shfl_xor(cd, m));
    if (fr == 0)                        // positive floats: int compare == float compare
      atomicMax((int*)(out + (size_t)row * (CC + 1) + CC), __float_as_int(cd));
  }
}

extern "C" void kernel_launch(void* const* d_in, const int* in_sizes, int n_in,
                              void* d_out, int out_size, void* d_ws, size_t ws_size,
                              hipStream_t stream) {
  const float* y  = (const float*)d_in[0];   // [512, 1000]
  const float* kW = (const float*)d_in[1];   // [512, 1000]
  float* out = (float*)d_out;                // [512, 1001]

  char* ws = (char*)d_ws;
  unsigned short* Wt = (unsigned short*)(ws);                   // 1024*528*2 = 1081 KB
  float* normp       = (float*)(ws + (1088 << 10));             // 16 KB
  int*   wjp         = (int*)(ws + (1104 << 10));               // 2 KB
  float* wymaxp      = (float*)(ws + (1106 << 10));             // 2 KB

  void* args[] = {(void*)&y, (void*)&kW, (void*)&Wt, (void*)&normp,
                  (void*)&wjp, (void*)&wymaxp, (void*)&out};
  hipLaunchCooperativeKernel((const void*)lm_coop, dim3(512), dim3(256),
                             args, 0, stream);
}

// Round 10
// 72.611 us; speedup vs baseline: 2.6977x; 2.6977x over previous
//
#include <hip/hip_runtime.h>
#include <math.h>

// Problem constants (fixed by setup_inputs)
constexpr int BB = 512;    // batch (GEMM M)
constexpr int DD = 512;    // features (GEMM K)
constexpr int CC = 1000;   // classes
constexpr int CP = 1024;   // padded classes (GEMM N)
constexpr int RP = 528;    // padded row length (shorts): 1056 B, 16B-aligned,
                           // breaks 256B/1KB channel periodicity
constexpr int NDC = 8;     // norm d-chunks (64 d each)
constexpr float EPSF = 0.3f;

// TWO launches (R8 structure — best measured; coop-sync single kernel was a
// 2.5x regression in R9: grid.sync() costs ~125 us on 8-XCD gfx950).
// K[b,c]^2 = nj[b] + nc[c] - 2*dot(col_jb, col_c); dot via bf16 MFMA.
// Q[b,:] == row j_b of the transposed Wt and nj[b] == nc[j_b], so no gather
// pass and no Q buffer; the GEMM A-side indexes Wt rows through wj[].
//   lm_build : blocks 0-127  : argmax/ymax per row (1 wave/row) + fused y->out
//              blocks 128-255: kW -> Wt (bf16 transpose via LDS, zero-padded,
//              coalesced 16B writes) + fp32 column-norm partials (8 d-chunks;
//              128 blocks so the transpose pole spans half the CUs, not 1/4)
//   lm_gemm  : 2048 waves, one 16x16 (batch x class) tile each. All 32
//              fragments register-prefetched, then 16 MFMAs back-to-back.
//              Epilogue: candidates in-register, butterfly row-max, atomicMax
//              (float-as-int; all candidates positive — validated R5-R8).
//
// ws layout (16B-aligned):
//   Wt    [1024*528] ushort @ 0        (1081 KB)
//   normp [8*1024]   float  @ 1088 KB  (32 KB)
//   wj    [512]      int    @ +32 KB
//   wymax [512]      float  @ +2 KB

using short8 = __attribute__((ext_vector_type(8))) short;
using us8    = __attribute__((ext_vector_type(8))) unsigned short;
using f32x4  = __attribute__((ext_vector_type(4))) float;

__device__ inline unsigned short f2bf(float f) {   // RNE float->bf16
  unsigned u = __float_as_uint(f);
  return (unsigned short)((u + 0x7FFFu + ((u >> 16) & 1u)) >> 16);
}

__global__ __launch_bounds__(256) void lm_build(const float* __restrict__ y,
                                                const float* __restrict__ kW,
                                                unsigned short* __restrict__ Wt,
                                                float* __restrict__ normp,
                                                int* __restrict__ wj,
                                                float* __restrict__ wymax,
                                                float* __restrict__ out) {
  const int t = threadIdx.x;
  const int w = t >> 6, lane = t & 63;

  if (blockIdx.x < 128) {
    // ---------- argmax/ymax, one wave per row, + fused y->out copy ----------
    const int b = blockIdx.x * 4 + w;
    const float* yr = y + (size_t)b * CC;
    float bv = -INFINITY; int bi = 0;
    #pragma unroll
    for (int k = 0; k < 4; ++k) {
      const int c4 = (lane + k * 64) * 4;   // ascending per lane -> '>' keeps lowest
      if (c4 < CC) {
        const float4 v = *(const float4*)(yr + c4);
        if (v.x > bv) { bv = v.x; bi = c4; }
        if (v.y > bv) { bv = v.y; bi = c4 + 1; }
        if (v.z > bv) { bv = v.z; bi = c4 + 2; }
        if (v.w > bv) { bv = v.w; bi = c4 + 3; }
        float* orow = out + (size_t)b * (CC + 1) + c4;  // scalar stores (row stride 1001)
        orow[0] = v.x; orow[1] = v.y; orow[2] = v.z; orow[3] = v.w;
      }
    }
    #pragma unroll
    for (int off = 32; off > 0; off >>= 1) {
      const float ov = __shfl_down(bv, off);
      const int   oi = __shfl_down(bi, off);
      if (ov > bv || (ov == bv && oi < bi)) { bv = ov; bi = oi; }
    }
    if (lane == 0) { wj[b] = bi; wymax[b] = bv; }
  } else {
    // ---------- transpose kW -> Wt (LDS-staged) + fp32 norm partials ----------
    __shared__ float nsum[4][64];
    __shared__ __align__(16) unsigned short tile[64][72];  // 64c x 64d staging (+pad)
    const int blk = blockIdx.x - 128;    // 0..127
    const int cs = blk & 15, dc = blk >> 4;   // 16 c-slices x 8 d-chunks
    const int c0 = cs * 64, d0 = dc * 64;
    const int c = c0 + lane;
    const bool cok = (c < CC);
    float s = 0.f;
    #pragma unroll 8
    for (int it = 0; it < 16; ++it) {
      const int dd = w + it * 4;                    // 0..63
      const float v = cok ? kW[(size_t)(d0 + dd) * CC + c] : 0.f;
      s += v * v;
      tile[lane][dd] = f2bf(v);
    }
    nsum[w][lane] = s;
    __syncthreads();
    if (w == 0)
      normp[(size_t)dc * CP + c] = nsum[0][lane] + nsum[1][lane] + nsum[2][lane] + nsum[3][lane];
    // coalesced 16B writes of the transposed tile
    #pragma unroll
    for (int k = 0; k < 2; ++k) {
      const int lin = t * 2 + k;                    // 0..511
      const int cc = lin >> 3, ch = lin & 7;
      *(us8*)(Wt + (size_t)(c0 + cc) * RP + d0 + ch * 8) =
          *(const us8*)(&tile[cc][ch * 8]);
    }
  }
}

__global__ __launch_bounds__(256) void lm_gemm(const unsigned short* __restrict__ Wt,
                                               const float* __restrict__ y,
                                               const float* __restrict__ normp,
                                               const int* __restrict__ wj,
                                               const float* __restrict__ wymax,
                                               float* __restrict__ out) {
  const int t = threadIdx.x;
  const int lane = t & 63;
  const int tile = blockIdx.x * 4 + (t >> 6);   // 0..2047
  const int m0 = (tile >> 6) * 16;              // 32 m-tiles (batch)
  const int n0 = (tile & 63) * 16;              // 64 n-tiles (classes)

  const int fr = lane & 15;            // A: m-row / B: n-row / C: col
  const int quad = lane >> 4;          // A/B: k-offset quad*8; C: row quad*4+reg

  const int ja = wj[m0 + fr];          // A-side: row j of Wt IS column j of kW
  const unsigned short* ap = Wt + (size_t)ja * RP + quad * 8;
  const unsigned short* bp = Wt + (size_t)(n0 + fr) * RP + quad * 8;

  // register-prefetch the whole K-slab (32 independent 16B loads), then MFMA
  short8 af[16], bf[16];
  #pragma unroll
  for (int k = 0; k < 16; ++k) {
    af[k] = *(const short8*)(ap + k * 32);
    bf[k] = *(const short8*)(bp + k * 32);
  }
  f32x4 acc = {0.f, 0.f, 0.f, 0.f};
  #pragma unroll
  for (int k = 0; k < 16; ++k)
    acc = __builtin_amdgcn_mfma_f32_16x16x32_bf16(af[k], bf[k], acc, 0, 0, 0);

  // ---- fused epilogue: candidates + butterfly row-max + atomicMax ----
  const int col = n0 + fr;             // class
  const bool cok = (col < CC);
  float nc = 0.f;
  if (cok) {
    #pragma unroll
    for (int dc = 0; dc < NDC; ++dc) nc += normp[(size_t)dc * CP + col];
  }

  #pragma unroll
  for (int r = 0; r < 4; ++r) {
    const int row = m0 + quad * 4 + r; // batch
    float cd = -INFINITY;
    if (cok) {
      const int jr = wj[row];
      float nj = 0.f;
      #pragma unroll
      for (int dc = 0; dc < NDC; ++dc) nj += normp[(size_t)dc * CP + jr];
      const float yv = y[(size_t)row * CC + col];
      const float ym = wymax[row];
      const float k2 = nj + nc - 2.f * acc[r];
      cd = (yv == ym) ? -INFINITY : yv + EPSF * sqrtf(fmaxf(k2, 0.f) + 1e-10f);
    }
    #pragma unroll
    for (int m = 1; m < 16; m <<= 1)   // reduce over the 16 cols (same quad group)
      cd = fmaxf(cd, __shfl_xor(cd, m));
    if (fr == 0)                        // positive floats: int compare == float compare
      atomicMax((int*)(out + (size_t)row * (CC + 1) + CC), __float_as_int(cd));
  }
}

extern "C" void kernel_launch(void* const* d_in, const int* in_sizes, int n_in,
                              void* d_out, int out_size, void* d_ws, size_t ws_size,
                              hipStream_t stream) {
  const float* y  = (const float*)d_in[0];   // [512, 1000]
  const float* kW = (const float*)d_in[1];   // [512, 1000]
  float* out = (float*)d_out;                // [512, 1001]

  char* ws = (char*)d_ws;
  unsigned short* Wt = (unsigned short*)(ws);                   // 1024*528*2 = 1081 KB
  float* normp       = (float*)(ws + (1088 << 10));             // 32 KB
  int*   wjp         = (int*)(ws + (1120 << 10));               // 2 KB
  float* wymaxp      = (float*)(ws + (1122 << 10));             // 2 KB

  lm_build<<<256, 256, 0, stream>>>(y, kW, Wt, normp, wjp, wymaxp, out);
  lm_gemm<<<512, 256, 0, stream>>>(Wt, y, normp, wjp, wymaxp, out);
}